// Round 3
// baseline (963.962 us; speedup 1.0000x reference)
//
#include <hip/hip_runtime.h>
#include <math.h>

#define DIM 128
#define HID 512
#define BATCHN 16384
#define NSTEPS 20
#define ROWSTRIDE 131                 // DIM + 3 aug columns
#define SLICE (BATCHN * ROWSTRIDE)    // floats per trajectory step
#define BM 64                         // batch rows per block (2 groups of 32)
#define GR 32                         // rows per group
#define HCST 520                      // hc row stride (bf16)
#define YBST 136                      // ybf row stride (bf16)
#define REDST 18                      // red row stride (f32)

typedef __bf16 bf16_t;
typedef __bf16 bf16x8 __attribute__((ext_vector_type(8)));
typedef float floatx4 __attribute__((ext_vector_type(4)));

__device__ __forceinline__ float fast_tanh(float x) {
    float e = __expf(2.0f * x);
    return 1.0f - 2.0f / (e + 1.0f);
}

// ws layout: W1T bf16 [512][128] @0 ; W2T bf16 [128][512] @131072 ;
//            biasEff f32 [20][512] @262144
__global__ void prep_kernel(const float* __restrict__ W1, const float* __restrict__ b1,
                            const float* __restrict__ W2, const float* __restrict__ ts,
                            bf16_t* __restrict__ W1T, bf16_t* __restrict__ W2T,
                            float* __restrict__ biasEff) {
    int tid = blockIdx.x * blockDim.x + threadIdx.x;   // 0..65535
    {   int j = tid >> 7, k = tid & 127;               // W1T[j][k] = W1[k][j]
        W1T[j * DIM + k] = (bf16_t)W1[k * HID + j]; }
    {   int j = tid >> 9, k = tid & 511;               // W2T[j][k] = W2[k][j]
        W2T[j * HID + k] = (bf16_t)W2[k * DIM + j]; }
    if (tid < NSTEPS * HID) {                          // b1[j] + ts[s]*W1[128][j]
        int s = tid >> 9, j = tid & 511;
        biasEff[tid] = b1[j] + ts[s] * W1[DIM * HID + j];
    }
}

// ---------------- phase-stage helpers (all inlined, single-block bodies) ----

// GEMM1(X, s): hc_X = tanh(y_X @ W1 + biasEff[s]); also prefetch noise(X, s).
__device__ __forceinline__ void do_gemm1(
    int s, const bf16_t* __restrict__ ybfX, bf16_t* __restrict__ hcX,
    float (&nz)[2][4], const bf16x8 (&w1f)[4][4],
    const float* __restrict__ noises, int gRow0,
    const float* __restrict__ biasEff,
    int quad, int l15, int w, int col)
{
    const float* nb = noises + (size_t)s * (BATCHN * DIM) + (size_t)gRow0 * DIM;
    #pragma unroll
    for (int m = 0; m < 2; ++m)
        #pragma unroll
        for (int i = 0; i < 4; ++i)
            nz[m][i] = nb[(size_t)(m * 16 + quad * 4 + i) * DIM + col];
    float bias[4];
    const float* be = biasEff + s * HID + w * 64;
    #pragma unroll
    for (int jn = 0; jn < 4; ++jn) bias[jn] = be[jn * 16 + l15];

    const int rsw = (l15 >> 3) << 4;   // read rows m*16+l15: swz bit = l15>>3
    bf16x8 a1[2][4];
    #pragma unroll
    for (int m = 0; m < 2; ++m)
        #pragma unroll
        for (int k0 = 0; k0 < 4; ++k0)
            a1[m][k0] = *(const bf16x8*)(ybfX + (m * 16 + l15) * YBST +
                                         ((k0 * 32 + quad * 8) ^ rsw));
    const int wsw = (quad >> 1) << 4;  // write rows m*16+quad*4+i: swz = quad>>1
    #pragma unroll
    for (int jn = 0; jn < 4; ++jn) {
        floatx4 acc1[2];
        acc1[0] = (floatx4){0.f, 0.f, 0.f, 0.f};
        acc1[1] = (floatx4){0.f, 0.f, 0.f, 0.f};
        #pragma unroll
        for (int k0 = 0; k0 < 4; ++k0) {
            acc1[0] = __builtin_amdgcn_mfma_f32_16x16x32_bf16(a1[0][k0], w1f[jn][k0], acc1[0], 0, 0, 0);
            acc1[1] = __builtin_amdgcn_mfma_f32_16x16x32_bf16(a1[1][k0], w1f[jn][k0], acc1[1], 0, 0, 0);
        }
        #pragma unroll
        for (int m = 0; m < 2; ++m)
            #pragma unroll
            for (int i = 0; i < 4; ++i)
                hcX[(m * 16 + quad * 4 + i) * HCST + ((w * 64 + jn * 16 + l15) ^ wsw)] =
                    (bf16_t)fast_tanh(acc1[m][i] + bias[jn]);
    }
}

// GEMM2+epilogue(Y, s): U = hc_Y @ W2 + b2 ; SDE update ; write outImg/ybf/red.
__device__ __forceinline__ void do_gemm2_epi(
    const bf16_t* __restrict__ hcY, bf16_t* __restrict__ ybfY,
    float* __restrict__ outY, float* __restrict__ redY,
    float (&yv)[2][4], const float (&nz)[2][4],
    const bf16x8 (&w2f)[16], float b2c, float dtv, float sqv,
    int quad, int l15, int w, int col)
{
    const int rsw = (l15 >> 3) << 4;
    floatx4 accu[2];
    accu[0] = (floatx4){0.f, 0.f, 0.f, 0.f};
    accu[1] = (floatx4){0.f, 0.f, 0.f, 0.f};
    #pragma unroll
    for (int k0 = 0; k0 < 16; ++k0) {
        bf16x8 a20 = *(const bf16x8*)(hcY + l15 * HCST + ((k0 * 32 + quad * 8) ^ rsw));
        bf16x8 a21 = *(const bf16x8*)(hcY + (16 + l15) * HCST + ((k0 * 32 + quad * 8) ^ rsw));
        accu[0] = __builtin_amdgcn_mfma_f32_16x16x32_bf16(a20, w2f[k0], accu[0], 0, 0, 0);
        accu[1] = __builtin_amdgcn_mfma_f32_16x16x32_bf16(a21, w2f[k0], accu[1], 0, 0, 0);
    }
    const int wsw = (quad >> 1) << 4;
    #pragma unroll
    for (int m = 0; m < 2; ++m)
        #pragma unroll
        for (int i = 0; i < 4; ++i) {
            int r = m * 16 + quad * 4 + i;
            float u  = accu[m][i] + b2c;
            float y  = yv[m][i];
            float yn = y + (u - y) * dtv + sqv * nz[m][i];   // ALPHA=SIGMA=1
            yv[m][i] = yn;
            outY[r * ROWSTRIDE + col] = yn;
            ybfY[r * YBST + (col ^ wsw)] = (bf16_t)yn;
            float pdu = u * nz[m][i];
            float pen = u * u;
            pdu += __shfl_xor(pdu, 1); pen += __shfl_xor(pen, 1);
            pdu += __shfl_xor(pdu, 2); pen += __shfl_xor(pen, 2);
            pdu += __shfl_xor(pdu, 4); pen += __shfl_xor(pen, 4);
            pdu += __shfl_xor(pdu, 8); pen += __shfl_xor(pen, 8);
            if (l15 == 0) {
                redY[r * REDST + w * 2]     = pdu;
                redY[r * REDST + w * 2 + 1] = pen;
            }
        }
}

// combine(X, s): 8 col-wave partials -> aug accumulators -> outImg aug columns
__device__ __forceinline__ void do_comb(
    const float* __restrict__ redX, float* __restrict__ outX,
    float& a0, float& a2v, bool act, int r, float dtv, float sqv)
{
    if (act) {
        const float* rp = redX + r * REDST;
        float du = 0.f, en = 0.f;
        #pragma unroll
        for (int k = 0; k < 8; ++k) { du += rp[k * 2]; en += rp[k * 2 + 1]; }
        a0  += du * sqv;
        a2v += 0.5f * en * dtv;
        float* o = outX + r * ROWSTRIDE + DIM;
        o[0] = a0; o[1] = a0; o[2] = a2v;   // udw == udw_det numerically
    }
}

// stream(Z, s): 32x131 f32 LDS image -> 16768B line-aligned global region
__device__ __forceinline__ void do_stream(
    const float* __restrict__ src, float* __restrict__ dst, int tid)
{
    const floatx4* s4 = (const floatx4*)src;
    floatx4* d4 = (floatx4*)dst;
    for (int i = tid; i < GR * ROWSTRIDE / 4; i += 512)
        d4[i] = s4[i];
}

// ------------------------------- fused kernel -------------------------------
// 256 blocks x 512 threads (8 waves), BM=64 rows (groups A=0..31, B=32..63),
// 2-phase software pipeline: even phase p=2s:   GEMM1(A,s) | GEMM2+epi(B,s-1)
//                                              | comb(A,s-1) | stream(B,s-2)
//                            odd  phase p=2s+1: GEMM1(B,s) | GEMM2+epi(A,s)
//                                              | comb(B,s-1) | stream(A,s-1)
// One barrier per phase (2/step). Weights reg-resident (w1f 64 + w2f 64).
// LDS (155808 B): ybfA@0 ybfB@8704 (bf16[32][136], XOR-swizzled)
//   hcA@17408 hcB@50688 (bf16[32][520], XOR-swizzled)
//   outImg A0@83968 A1@100736 B0@117504 B1@134272 (f32[32][131], dbuf/group)
//   redA@151040 redB@153344 (f32[32][18]) ; dtbl@155648 sqtbl@155728 (f32[20])
__global__ __launch_bounds__(512, 2)
void fused_kernel(const float* __restrict__ y0, float* __restrict__ traj,
                  const float* __restrict__ noises,
                  const bf16_t* __restrict__ W1T, const bf16_t* __restrict__ W2T,
                  const float* __restrict__ biasEff, const float* __restrict__ b2,
                  const float* __restrict__ ts) {
    __shared__ __align__(16) char smem[155808];
    bf16_t* ybfA = (bf16_t*)(smem);
    bf16_t* ybfB = (bf16_t*)(smem + 8704);
    bf16_t* hcA  = (bf16_t*)(smem + 17408);
    bf16_t* hcB  = (bf16_t*)(smem + 50688);
    float*  outA0 = (float*)(smem + 83968);
    float*  outA1 = (float*)(smem + 100736);
    float*  outB0 = (float*)(smem + 117504);
    float*  outB1 = (float*)(smem + 134272);
    float*  redA = (float*)(smem + 151040);
    float*  redB = (float*)(smem + 153344);
    float*  dtbl = (float*)(smem + 155648);
    float*  sqtbl = (float*)(smem + 155728);

    const int tid  = threadIdx.x;
    const int lane = tid & 63;
    const int w    = tid >> 6;      // wave 0..7
    const int quad = lane >> 4;
    const int l15  = lane & 15;
    const int row0 = blockIdx.x * BM;
    const int col  = w * 16 + l15;  // output column for GEMM2/epilogue

    // ---- persistent weight fragments ----
    bf16x8 w1f[4][4];
    {
        const bf16_t* W1w = W1T + (size_t)(w * 64) * DIM;
        #pragma unroll
        for (int jn = 0; jn < 4; ++jn)
            #pragma unroll
            for (int k0 = 0; k0 < 4; ++k0)
                w1f[jn][k0] = *(const bf16x8*)(W1w + (jn * 16 + l15) * DIM + k0 * 32 + quad * 8);
    }
    bf16x8 w2f[16];
    {
        const bf16_t* W2r = W2T + (size_t)col * HID + quad * 8;
        #pragma unroll
        for (int k0 = 0; k0 < 16; ++k0)
            w2f[k0] = *(const bf16x8*)(W2r + k0 * 32);
    }
    const float b2c = b2[col];

    // ---- init: y0 -> regs + ybf + outImg buf0 ; dt tables ; slice-0 ----
    float yvA[2][4], yvB[2][4], nzA[2][4], nzB[2][4];
    float augA0 = 0.f, augA2 = 0.f, augB0 = 0.f, augB2 = 0.f;
    {
        const int wsw = (quad >> 1) << 4;
        const float* y0b = y0 + (size_t)row0 * DIM;
        #pragma unroll
        for (int m = 0; m < 2; ++m)
            #pragma unroll
            for (int i = 0; i < 4; ++i) {
                int r = m * 16 + quad * 4 + i;
                float va = y0b[(size_t)r * DIM + col];
                float vb = y0b[(size_t)(r + GR) * DIM + col];
                yvA[m][i] = va;  yvB[m][i] = vb;
                outA0[r * ROWSTRIDE + col] = va;
                outB0[r * ROWSTRIDE + col] = vb;
                ybfA[r * YBST + (col ^ wsw)] = (bf16_t)va;
                ybfB[r * YBST + (col ^ wsw)] = (bf16_t)vb;
            }
        if (tid < GR) {
            float* oa = outA0 + tid * ROWSTRIDE + DIM;
            oa[0] = 0.f; oa[1] = 0.f; oa[2] = 0.f;
        } else if (tid < 2 * GR) {
            float* ob = outB0 + (tid - GR) * ROWSTRIDE + DIM;
            ob[0] = 0.f; ob[1] = 0.f; ob[2] = 0.f;
        }
        if (tid < NSTEPS) {
            float d = ts[tid + 1] - ts[tid];
            dtbl[tid] = d;
            sqtbl[tid] = sqrtf(d);
        }
        if (blockIdx.x == 0 && tid <= NSTEPS)
            traj[(size_t)(NSTEPS + 1) * SLICE + tid] = ts[tid];
    }
    __syncthreads();
    // slice 0 out
    do_stream(outA0, traj + (size_t)row0 * ROWSTRIDE, tid);
    do_stream(outB0, traj + (size_t)(row0 + GR) * ROWSTRIDE, tid);

    // ---- phase pipeline ----
    #pragma unroll 1
    for (int p = 0; p <= 2 * NSTEPS + 2; ++p) {
        const int h = p >> 1;
        if ((p & 1) == 0) {
            const int sg1 = h, sg2 = h - 1, sc = h - 1, ss = h - 2;
            const bool g1 = (sg1 < NSTEPS);
            const bool g2 = (sg2 >= 0) && (sg2 < NSTEPS);
            const bool gc = (sc >= 0) && (sc < NSTEPS);
            const bool gs = (ss >= 0) && (ss < NSTEPS);
            float* outE = (sg2 >= 0 && (sg2 & 1)) ? outB1 : outB0;
            float* outC = (sc >= 0 && (sc & 1)) ? outA1 : outA0;
            const float* outS = (ss >= 0 && (ss & 1)) ? outB1 : outB0;
            float dtE = g2 ? dtbl[sg2] : 0.f, sqE = g2 ? sqtbl[sg2] : 0.f;
            float dtC = gc ? dtbl[sc] : 0.f, sqC = gc ? sqtbl[sc] : 0.f;
            if (g1 && g2 && gc && gs) {         // steady: one basic block
                do_gemm1(sg1, ybfA, hcA, nzA, w1f, noises, row0, biasEff, quad, l15, w, col);
                do_gemm2_epi(hcB, ybfB, outE, redB, yvB, nzB, w2f, b2c, dtE, sqE, quad, l15, w, col);
                do_comb(redA, outC, augA0, augA2, tid < GR, tid, dtC, sqC);
                do_stream(outS, traj + (size_t)(ss + 1) * SLICE + (size_t)(row0 + GR) * ROWSTRIDE, tid);
            } else {
                if (g1) do_gemm1(sg1, ybfA, hcA, nzA, w1f, noises, row0, biasEff, quad, l15, w, col);
                if (g2) do_gemm2_epi(hcB, ybfB, outE, redB, yvB, nzB, w2f, b2c, dtE, sqE, quad, l15, w, col);
                if (gc) do_comb(redA, outC, augA0, augA2, tid < GR, tid, dtC, sqC);
                if (gs) do_stream(outS, traj + (size_t)(ss + 1) * SLICE + (size_t)(row0 + GR) * ROWSTRIDE, tid);
            }
        } else {
            const int sg1 = h, sg2 = h, sc = h - 1, ss = h - 1;
            const bool g1 = (sg1 < NSTEPS);
            const bool g2 = (sg2 < NSTEPS);
            const bool gc = (sc >= 0) && (sc < NSTEPS);
            const bool gs = (ss >= 0) && (ss < NSTEPS);
            float* outE = (sg2 & 1) ? outA1 : outA0;
            float* outC = (sc >= 0 && (sc & 1)) ? outB1 : outB0;
            const float* outS = (ss >= 0 && (ss & 1)) ? outA1 : outA0;
            float dtE = g2 ? dtbl[sg2] : 0.f, sqE = g2 ? sqtbl[sg2] : 0.f;
            float dtC = gc ? dtbl[sc] : 0.f, sqC = gc ? sqtbl[sc] : 0.f;
            if (g1 && g2 && gc && gs) {         // steady: one basic block
                do_gemm1(sg1, ybfB, hcB, nzB, w1f, noises, row0 + GR, biasEff, quad, l15, w, col);
                do_gemm2_epi(hcA, ybfA, outE, redA, yvA, nzA, w2f, b2c, dtE, sqE, quad, l15, w, col);
                do_comb(redB, outC, augB0, augB2, (tid >= GR) && (tid < 2 * GR), tid & (GR - 1), dtC, sqC);
                do_stream(outS, traj + (size_t)(ss + 1) * SLICE + (size_t)row0 * ROWSTRIDE, tid);
            } else {
                if (g1) do_gemm1(sg1, ybfB, hcB, nzB, w1f, noises, row0 + GR, biasEff, quad, l15, w, col);
                if (g2) do_gemm2_epi(hcA, ybfA, outE, redA, yvA, nzA, w2f, b2c, dtE, sqE, quad, l15, w, col);
                if (gc) do_comb(redB, outC, augB0, augB2, (tid >= GR) && (tid < 2 * GR), tid & (GR - 1), dtC, sqC);
                if (gs) do_stream(outS, traj + (size_t)(ss + 1) * SLICE + (size_t)row0 * ROWSTRIDE, tid);
            }
        }
        __syncthreads();
    }
}

extern "C" void kernel_launch(void* const* d_in, const int* in_sizes, int n_in,
                              void* d_out, int out_size, void* d_ws, size_t ws_size,
                              hipStream_t stream) {
    const float* y0     = (const float*)d_in[0];
    const float* W1     = (const float*)d_in[1];
    const float* b1     = (const float*)d_in[2];
    const float* W2     = (const float*)d_in[3];
    const float* b2     = (const float*)d_in[4];
    const float* noises = (const float*)d_in[5];
    const float* ts     = (const float*)d_in[6];
    float* out = (float*)d_out;

    bf16_t* W1T     = (bf16_t*)d_ws;
    bf16_t* W2T     = (bf16_t*)((char*)d_ws + 131072);
    float*  biasEff = (float*)((char*)d_ws + 262144);

    prep_kernel<<<256, 256, 0, stream>>>(W1, b1, W2, ts, W1T, W2T, biasEff);
    fused_kernel<<<BATCHN / BM, 512, 0, stream>>>(y0, out, noises, W1T, W2T,
                                                  biasEff, b2, ts);
}